// Round 2
// baseline (239.602 us; speedup 1.0000x reference)
//
#include <hip/hip_runtime.h>

// ConvexWidthUpsampler fused kernel, packed-fp32 (v_pk_fma_f32) version.
// B=16, C=1, H=512, W=512, up=(1,3). Output [16,1,512,1536] f32.

#define BB 16
#define HH 512
#define WW 512
#define HID 32

typedef float f32x2 __attribute__((ext_vector_type(2)));
typedef float f32x4 __attribute__((ext_vector_type(4)));

__device__ __forceinline__ f32x2 pk_fma(f32x2 a, f32x2 b, f32x2 c) {
    f32x2 d;
    asm("v_pk_fma_f32 %0, %1, %2, %3" : "=v"(d) : "v"(a), "v"(b), "v"(c));
    return d;
}

// Transpose w1 [32][9] -> w1t [9][32] so channel pairs are contiguous.
__global__ void prep_w1t(const float* __restrict__ w1, float* __restrict__ w1t) {
    const int i = threadIdx.x;
    if (i < HID * 9) {
        const int c = i / 9, k = i % 9;
        w1t[k * HID + c] = w1[i];
    }
}

__global__ __launch_bounds__(256) void convex_upsample_pk(
    const float* __restrict__ x,     // [16,1,512,512]
    const float* __restrict__ w1t,   // [9,32] transposed
    const float* __restrict__ b1,    // [32]
    const float* __restrict__ alpha, // [32]
    const float* __restrict__ w2,    // [27,32]
    const float* __restrict__ b2,    // [27]
    float* __restrict__ out)         // [16,1,512,1536]
{
    const int p    = blockIdx.x * 256 + threadIdx.x;
    const int wcol = p & (WW - 1);
    const int t    = p >> 9;
    const int hrow = t & (HH - 1);
    const int bidx = t >> 9;

    const float* xb = x + (size_t)bidx * (HH * WW);

    // 3x3 neighborhood with zero padding
    float xv[9];
#pragma unroll
    for (int ki = 0; ki < 3; ++ki) {
        const int hy = hrow + ki - 1;
        const bool hok = (unsigned)hy < (unsigned)HH;
#pragma unroll
        for (int kj = 0; kj < 3; ++kj) {
            const int wx = wcol + kj - 1;
            const bool ok = hok && ((unsigned)wx < (unsigned)WW);
            xv[ki * 3 + kj] = ok ? xb[hy * WW + wx] : 0.0f;
        }
    }

    // conv3x3 over packed channel pairs: acc[c2] = (h[2c2], h[2c2+1])
    f32x2 acc[16];
#pragma unroll
    for (int c2 = 0; c2 < 16; ++c2)
        acc[c2] = *(const f32x2*)(b1 + 2 * c2);

#pragma unroll
    for (int k = 0; k < 9; ++k) {
        f32x2 xk; xk.x = xv[k]; xk.y = xv[k];
        const f32x4* wr = (const f32x4*)(w1t + k * HID);
#pragma unroll
        for (int c4 = 0; c4 < 8; ++c4) {
            const f32x4 w4 = wr[c4];
            acc[2 * c4]     = pk_fma(__builtin_shufflevector(w4, w4, 0, 1), xk, acc[2 * c4]);
            acc[2 * c4 + 1] = pk_fma(__builtin_shufflevector(w4, w4, 2, 3), xk, acc[2 * c4 + 1]);
        }
    }

    // PReLU: h = max(v,0) + alpha*min(v,0)   (packed pairs kept packed)
    f32x2 h2[16];
#pragma unroll
    for (int c2 = 0; c2 < 16; ++c2) {
        const f32x2 a2 = *(const f32x2*)(alpha + 2 * c2);
        const f32x2 v = acc[c2];
        h2[c2].x = fmaxf(v.x, 0.0f) + a2.x * fminf(v.x, 0.0f);
        h2[c2].y = fmaxf(v.y, 0.0f) + a2.y * fminf(v.y, 0.0f);
    }

    // Per output sub-pixel v: 9 logits (j = k*3+v) -> softmax -> combine
    const size_t ob = ((size_t)(bidx * HH + hrow) * (WW * 3)) + (size_t)wcol * 3;
#pragma unroll
    for (int v = 0; v < 3; ++v) {
        float m[9];
#pragma unroll
        for (int k = 0; k < 9; ++k) {
            const int j = k * 3 + v;
            f32x2 s; s.x = b2[j]; s.y = 0.0f;
            const f32x4* wr = (const f32x4*)(w2 + j * HID);
#pragma unroll
            for (int c4 = 0; c4 < 8; ++c4) {
                const f32x4 w4 = wr[c4];
                s = pk_fma(__builtin_shufflevector(w4, w4, 0, 1), h2[2 * c4], s);
                s = pk_fma(__builtin_shufflevector(w4, w4, 2, 3), h2[2 * c4 + 1], s);
            }
            m[k] = s.x + s.y;
        }

        float mx = m[0];
#pragma unroll
        for (int k = 1; k < 9; ++k) mx = fmaxf(mx, m[k]);
        float ssum = 0.0f, occ = 0.0f;
#pragma unroll
        for (int k = 0; k < 9; ++k) {
            const float e = __expf(m[k] - mx);
            ssum += e;
            occ = fmaf(xv[k], e, occ);
        }
        out[ob + v] = occ * __builtin_amdgcn_rcpf(ssum);
    }
}

extern "C" void kernel_launch(void* const* d_in, const int* in_sizes, int n_in,
                              void* d_out, int out_size, void* d_ws, size_t ws_size,
                              hipStream_t stream) {
    // setup_inputs order: x, target_h, target_w, w1, b1, alpha, w2, b2
    const float* x     = (const float*)d_in[0];
    const float* w1    = (const float*)d_in[3];
    const float* b1    = (const float*)d_in[4];
    const float* alpha = (const float*)d_in[5];
    const float* w2    = (const float*)d_in[6];
    const float* b2    = (const float*)d_in[7];
    float* out = (float*)d_out;
    float* w1t = (float*)d_ws;   // 9*32 floats

    hipLaunchKernelGGL(prep_w1t, dim3(1), dim3(320), 0, stream, w1, w1t);

    const int total  = BB * HH * WW;
    const int blocks = total / 256;
    hipLaunchKernelGGL(convex_upsample_pk, dim3(blocks), dim3(256), 0, stream,
                       x, w1t, b1, alpha, w2, b2, out);
}

// Round 3
// 162.664 us; speedup vs baseline: 1.4730x; 1.4730x over previous
//
#include <hip/hip_runtime.h>

// ConvexWidthUpsampler fused, scalar-FMA register-economical schedule.
// B=16, C=1, H=512, W=512, up=(1,3). Output [16,1,512,1536] f32.
//
// Schedule: m[27] accumulators; per channel c: h_c = conv3x3 row + PReLU,
// then 27 FMAs into m[]. Peak live regs ~45 -> no rematerialization.
// w2 pre-transposed to [32][27] and pre-scaled by log2(e); b2 pre-scaled,
// so softmax = raw v_exp_f32 (2^x), no max-subtraction (logits O(1)).

#define BB 16
#define HH 512
#define WW 512
#define HID 32
#define NM 27
#define LOG2E 1.44269504088896340736f

__global__ void prep_weights(const float* __restrict__ w2,
                             const float* __restrict__ b2,
                             float* __restrict__ w2t,   // [32][27], scaled
                             float* __restrict__ b2s) { // [27], scaled
    const int i = threadIdx.x + blockIdx.x * 1024;
    if (i < NM * HID) {
        const int j = i / HID, c = i % HID;
        w2t[c * NM + j] = w2[i] * LOG2E;
    }
    if (i < NM) b2s[i] = b2[i] * LOG2E;
}

__global__ __launch_bounds__(256, 4) void convex_upsample_f32(
    const float* __restrict__ x,     // [16,1,512,512]
    const float* __restrict__ w1,    // [32,9]
    const float* __restrict__ b1,    // [32]
    const float* __restrict__ alpha, // [32]
    const float* __restrict__ w2t,   // [32,27] scaled by log2e
    const float* __restrict__ b2s,   // [27] scaled by log2e
    float* __restrict__ out)         // [16,1,512,1536]
{
    const int p    = blockIdx.x * 256 + threadIdx.x;
    const int wcol = p & (WW - 1);
    const int t    = p >> 9;
    const int hrow = t & (HH - 1);
    const int bidx = t >> 9;

    const float* xb = x + (size_t)bidx * (HH * WW);

    // 3x3 neighborhood with zero padding
    float xv[9];
#pragma unroll
    for (int ki = 0; ki < 3; ++ki) {
        const int hy = hrow + ki - 1;
        const bool hok = (unsigned)hy < (unsigned)HH;
#pragma unroll
        for (int kj = 0; kj < 3; ++kj) {
            const int wx = wcol + kj - 1;
            const bool ok = hok && ((unsigned)wx < (unsigned)WW);
            xv[ki * 3 + kj] = ok ? xb[hy * WW + wx] : 0.0f;
        }
    }

    // logits accumulate in-place; channels stream through one at a time
    float m[NM];
#pragma unroll
    for (int j = 0; j < NM; ++j) m[j] = b2s[j];

#pragma unroll
    for (int c = 0; c < HID; ++c) {
        float h = b1[c];
#pragma unroll
        for (int k = 0; k < 9; ++k) h = fmaf(w1[c * 9 + k], xv[k], h);
        // PReLU: max(h,0) + alpha*min(h,0)
        h = fmaxf(h, 0.0f) + alpha[c] * fminf(h, 0.0f);
#pragma unroll
        for (int j = 0; j < NM; ++j) m[j] = fmaf(w2t[c * NM + j], h, m[j]);
    }

    // per-v softmax (base-2, pre-scaled logits, no max-sub) + convex combine
    const size_t ob = ((size_t)(bidx * HH + hrow) * (WW * 3)) + (size_t)wcol * 3;
#pragma unroll
    for (int v = 0; v < 3; ++v) {
        float ssum = 0.0f, acc = 0.0f;
#pragma unroll
        for (int k = 0; k < 9; ++k) {
            const float e = __builtin_amdgcn_exp2f(m[k * 3 + v]);
            ssum += e;
            acc = fmaf(xv[k], e, acc);
        }
        out[ob + v] = acc * __builtin_amdgcn_rcpf(ssum);
    }
}

extern "C" void kernel_launch(void* const* d_in, const int* in_sizes, int n_in,
                              void* d_out, int out_size, void* d_ws, size_t ws_size,
                              hipStream_t stream) {
    // setup_inputs order: x, target_h, target_w, w1, b1, alpha, w2, b2
    const float* x     = (const float*)d_in[0];
    const float* w1    = (const float*)d_in[3];
    const float* b1    = (const float*)d_in[4];
    const float* alpha = (const float*)d_in[5];
    const float* w2    = (const float*)d_in[6];
    const float* b2    = (const float*)d_in[7];
    float* out = (float*)d_out;

    float* w2t = (float*)d_ws;            // 32*27 floats
    float* b2s = w2t + HID * NM;          // 27 floats

    hipLaunchKernelGGL(prep_weights, dim3(1), dim3(1024), 0, stream, w2, b2, w2t, b2s);

    const int total  = BB * HH * WW;
    const int blocks = total / 256;
    hipLaunchKernelGGL(convex_upsample_f32, dim3(blocks), dim3(256), 0, stream,
                       x, w1, b1, alpha, w2t, b2s, out);
}

// Round 4
// 87.376 us; speedup vs baseline: 2.7422x; 1.8617x over previous
//
#include <hip/hip_runtime.h>
#include <hip/hip_bf16.h>

// ConvexWidthUpsampler: VALU conv3x3 (z) + MFMA fused [M1|bias|M2]·[xv,1,|z|]
// + softmax + convex combine.  B=16,C=1,H=512,W=512,up=(1,3). Out f32.
//
// PReLU(z) = 0.5(1+a)z + 0.5(1-a)|z|  =>  logits = M1·xv + bias' + M2·|z|
// M1 = W2 diag(.5(1+a)) W1 [27x9], M2 = W2 diag(.5(1-a)) [27x32],
// bias' = b2 + W2 diag(.5(1+a)) b1.  All pre-scaled by log2(e), bf16 hi+lo.
// A row per pixel (K=64): k0..8=xv, k9=1.0, k10..15=0, k16..47=|z|, k48..63=0.

#define BB 16
#define HH 512
#define WW 512
#define HID 32
#define NM 27
#define LOG2E 1.44269504088896340736f
#define ROWB 144  // LDS bytes per pixel row (64 bf16 = 128B used, +16 pad -> 2-way banks)

typedef short bf16x8 __attribute__((ext_vector_type(8)));
typedef float f32x4  __attribute__((ext_vector_type(4)));
typedef unsigned int u32;
typedef u32 u32x4 __attribute__((ext_vector_type(4)));

__device__ __forceinline__ u32 pk2(float a, float b) {
    __hip_bfloat162 h = __float22bfloat162_rn(make_float2(a, b));
    union { __hip_bfloat162 h2; u32 u; } cv; cv.h2 = h;
    return cv.u;
}

// ---------------- prep: build B matrix [2 terms][32 n][64 k] bf16 ----------
__global__ void prep_B(const float* __restrict__ w1, const float* __restrict__ b1,
                       const float* __restrict__ alpha, const float* __restrict__ w2,
                       const float* __restrict__ b2, __hip_bfloat16* __restrict__ wsB) {
    const int i = blockIdx.x * 256 + threadIdx.x;   // 0..2047
    if (i >= 2048) return;
    const int n = i >> 6, k = i & 63;
    float v = 0.0f;
    if (n < NM) {
        if (k < 9) {
            for (int c = 0; c < HID; ++c)
                v += w2[n * HID + c] * (0.5f * (1.0f + alpha[c])) * w1[c * 9 + k];
        } else if (k == 9) {
            v = b2[n];
            for (int c = 0; c < HID; ++c)
                v += w2[n * HID + c] * (0.5f * (1.0f + alpha[c])) * b1[c];
        } else if (k >= 16 && k < 48) {
            const int c = k - 16;
            v = w2[n * HID + c] * (0.5f * (1.0f - alpha[c]));
        }
    }
    v *= LOG2E;
    const __hip_bfloat16 hi = __float2bfloat16(v);
    const __hip_bfloat16 lo = __float2bfloat16(v - __bfloat162float(hi));
    wsB[n * 64 + k]        = hi;   // term 0
    wsB[2048 + n * 64 + k] = lo;   // term 1
}

// ---------------- main fused kernel ----------------------------------------
__global__ __launch_bounds__(256, 4) void convex_upsample_mfma(
    const float* __restrict__ x,      // [16,1,512,512]
    const float* __restrict__ w1,     // [32,9] f32
    const float* __restrict__ b1,     // [32] f32
    const __hip_bfloat16* __restrict__ wsB, // [2][32][64] bf16
    float* __restrict__ out)          // [16,1,512,1536]
{
    __shared__ char lds_raw[4][64 * ROWB];   // 36864 B, one region per wave

    const int tid  = threadIdx.x;
    const int wv   = tid >> 6;
    const int lane = tid & 63;
    const int l16  = lane & 15;
    const int lq   = lane >> 4;
    char* wbase = lds_raw[wv];

    const int p    = blockIdx.x * 256 + tid;
    const int wcol = p & (WW - 1);
    const int t    = p >> 9;
    const int hrow = t & (HH - 1);
    const int bidx = t >> 9;

    // B fragments: lane holds col n = nt*16+l16, k = kt*32 + lq*8 + i
    bf16x8 Bf[2][2][2];   // [term][kt][nt]
#pragma unroll
    for (int tm = 0; tm < 2; ++tm)
#pragma unroll
        for (int nt = 0; nt < 2; ++nt)
#pragma unroll
            for (int kt = 0; kt < 2; ++kt)
                Bf[tm][kt][nt] = *(const bf16x8*)(wsB + tm * 2048 + (nt * 16 + l16) * 64 + kt * 32 + lq * 8);

    // 3x3 neighborhood, zero padded
    const float* xb = x + (size_t)bidx * (HH * WW);
    float xv[9];
#pragma unroll
    for (int ki = 0; ki < 3; ++ki) {
        const int hy = hrow + ki - 1;
        const bool hok = (unsigned)hy < (unsigned)HH;
#pragma unroll
        for (int kj = 0; kj < 3; ++kj) {
            const int wx = wcol + kj - 1;
            const bool ok = hok && ((unsigned)wx < (unsigned)WW);
            xv[ki * 3 + kj] = ok ? xb[hy * WW + wx] : 0.0f;
        }
    }

    // write A row: xv, 1.0, zeros, |z|, zeros  (8 x ds_write_b128)
    char* myrow = wbase + lane * ROWB;
    *(u32x4*)(myrow)      = (u32x4){pk2(xv[0], xv[1]), pk2(xv[2], xv[3]),
                                    pk2(xv[4], xv[5]), pk2(xv[6], xv[7])};
    *(u32x4*)(myrow + 16) = (u32x4){pk2(xv[8], 1.0f), 0u, 0u, 0u};

    // z = W1*xv + b1 (f32 VALU), |z| -> bf16 pairs -> k16..47
#pragma unroll
    for (int q = 0; q < 4; ++q) {
        u32 d[4];
#pragma unroll
        for (int h = 0; h < 4; ++h) {
            const int c0 = q * 8 + h * 2;
            float za = b1[c0], zb = b1[c0 + 1];
#pragma unroll
            for (int k = 0; k < 9; ++k) {
                za = fmaf(w1[c0 * 9 + k], xv[k], za);
                zb = fmaf(w1[(c0 + 1) * 9 + k], xv[k], zb);
            }
            d[h] = pk2(fabsf(za), fabsf(zb));
        }
        *(u32x4*)(myrow + 32 + q * 16) = (u32x4){d[0], d[1], d[2], d[3]};
    }
    *(u32x4*)(myrow + 96)  = (u32x4){0u, 0u, 0u, 0u};
    *(u32x4*)(myrow + 112) = (u32x4){0u, 0u, 0u, 0u};

    // MFMA: 4 M-tiles x 2 N-tiles x 2 K-tiles x 2 terms; m scatter back to LDS
#pragma unroll
    for (int mt = 0; mt < 4; ++mt) {
        const char* arow = wbase + (mt * 16 + l16) * ROWB;
        const bf16x8 a0 = *(const bf16x8*)(arow + lq * 16);        // k 0..31 slice
        const bf16x8 a1 = *(const bf16x8*)(arow + 64 + lq * 16);   // k 32..63 slice
        f32x4 acc0 = {0.f, 0.f, 0.f, 0.f}, acc1 = {0.f, 0.f, 0.f, 0.f};
        acc0 = __builtin_amdgcn_mfma_f32_16x16x32_bf16(a0, Bf[0][0][0], acc0, 0, 0, 0);
        acc0 = __builtin_amdgcn_mfma_f32_16x16x32_bf16(a1, Bf[0][1][0], acc0, 0, 0, 0);
        acc0 = __builtin_amdgcn_mfma_f32_16x16x32_bf16(a0, Bf[1][0][0], acc0, 0, 0, 0);
        acc0 = __builtin_amdgcn_mfma_f32_16x16x32_bf16(a1, Bf[1][1][0], acc0, 0, 0, 0);
        acc1 = __builtin_amdgcn_mfma_f32_16x16x32_bf16(a0, Bf[0][0][1], acc1, 0, 0, 0);
        acc1 = __builtin_amdgcn_mfma_f32_16x16x32_bf16(a1, Bf[0][1][1], acc1, 0, 0, 0);
        acc1 = __builtin_amdgcn_mfma_f32_16x16x32_bf16(a0, Bf[1][0][1], acc1, 0, 0, 0);
        acc1 = __builtin_amdgcn_mfma_f32_16x16x32_bf16(a1, Bf[1][1][1], acc1, 0, 0, 0);
        // C: row(px) = mt*16 + lq*4 + r, col(j) = nt*16 + l16
        char* mbase = wbase + (mt * 16 + lq * 4) * ROWB + l16 * 4;
#pragma unroll
        for (int r = 0; r < 4; ++r) {
            *(float*)(mbase + r * ROWB)      = acc0[r];
            *(float*)(mbase + r * ROWB + 64) = acc1[r];   // j += 16 -> +64 bytes
        }
    }

    // read back this pixel's 27 logits (f32, 7 x ds_read_b128)
    f32x4 mv[7];
#pragma unroll
    for (int q = 0; q < 7; ++q)
        mv[q] = *(const f32x4*)(wbase + lane * ROWB + q * 16);

    // softmax (base-2, pre-scaled, no max-sub) + convex combine
    const size_t ob = ((size_t)(bidx * HH + hrow) * (WW * 3)) + (size_t)wcol * 3;
#pragma unroll
    for (int v = 0; v < 3; ++v) {
        float ssum = 0.0f, acc = 0.0f;
#pragma unroll
        for (int k = 0; k < 9; ++k) {
            const int j = k * 3 + v;
            const float e = __builtin_amdgcn_exp2f(mv[j >> 2][j & 3]);
            ssum += e;
            acc = fmaf(xv[k], e, acc);
        }
        out[ob + v] = acc * __builtin_amdgcn_rcpf(ssum);
    }
}

extern "C" void kernel_launch(void* const* d_in, const int* in_sizes, int n_in,
                              void* d_out, int out_size, void* d_ws, size_t ws_size,
                              hipStream_t stream) {
    // setup_inputs order: x, target_h, target_w, w1, b1, alpha, w2, b2
    const float* x     = (const float*)d_in[0];
    const float* w1    = (const float*)d_in[3];
    const float* b1    = (const float*)d_in[4];
    const float* alpha = (const float*)d_in[5];
    const float* w2    = (const float*)d_in[6];
    const float* b2    = (const float*)d_in[7];
    float* out = (float*)d_out;
    __hip_bfloat16* wsB = (__hip_bfloat16*)d_ws;   // 2*32*64 bf16 = 8 KB

    hipLaunchKernelGGL(prep_B, dim3(8), dim3(256), 0, stream, w1, b1, alpha, w2, b2, wsB);

    const int total  = BB * HH * WW;
    const int blocks = total / 256;   // 16384
    hipLaunchKernelGGL(convex_upsample_mfma, dim3(blocks), dim3(256), 0, stream,
                       x, w1, b1, wsB, out);
}